// Round 4
// baseline (151.505 us; speedup 1.0000x reference)
//
#include <hip/hip_runtime.h>
#include <hip/hip_bf16.h>

// CMOW word-matrix chain product — R11: right-to-left (suffix-product) chain
// so the per-step table gather is CONTIGUOUS (4x dwordx4 instead of 16
// strided dwords). sent:[1024,64] i32; table:[30001,784] f32; out:[1024,784].
//
// G = M_i @ G (i descending). A = M_i: lane(n16,q) holds A[m][8q+j] =
// M[m][8q..8q+7] — contiguous 32B row run -> 2 float4 loads per operand half.
// B = G lives in LDS (B-conv, swizzled), same as before. fp32 ~ hi+lo bf16,
// 3 products/tile via mfma_f32_16x16x32_bf16 (12 MFMA/step).
//
// R11 vs R10:
//  - chain direction flipped: per-step A-gather 16 strided dword -> 4
//    contiguous dwordx4 (4x fewer VMEM instructions, ~9x fewer line
//    segments/instr). Distinguishes request-rate-bound vs HBM-bytes-bound.
//  - strided gather pattern survives only in the once-per-chunk init
//    (B-frags of M_last).
//  - tree is left-associative: Yw = P_{2w} @ P_{2w+1}, F = Y0 @ Y1; waves
//    0,2 write A-conv partials, waves 1,3 B-conv (parity swapped vs R10).
//  - epilogue: acc = F directly (not F^T): predicated dword stores, 64B
//    coalesced across n16 lanes.

#define MD    28
#define MD2   784
#define SEQL  64
#define CHUNK 16
#define WPB   4

typedef __attribute__((ext_vector_type(8))) short bf16x8;
typedef __attribute__((ext_vector_type(4))) float floatx4;

#define LDS_FENCE() asm volatile("s_waitcnt lgkmcnt(0)" ::: "memory")

__device__ __forceinline__ unsigned short f2bf(float x) {
    unsigned u = __float_as_uint(x);
    unsigned r = u + 0x7FFFu + ((u >> 16) & 1u);
    return (unsigned short)(r >> 16);
}
__device__ __forceinline__ float bf2f(unsigned short h) {
    return __uint_as_float(((unsigned)h) << 16);
}

// pack 2 fp32 -> dword of 2 bf16 (RNE) via v_cvt_pk_bf16_f32
__device__ __forceinline__ unsigned pk_bf16(float x, float y) {
    float2 f; f.x = x; f.y = y;
    __hip_bfloat162 h2 = __float22bfloat162_rn(f);
    union { __hip_bfloat162 h; unsigned u; } cv; cv.h = h2;
    return cv.u;
}

union U4F { uint4 u; bf16x8 v; };

// 8 fp32 -> hi/lo bf16x8, then AND packed words with masks:
// words 0,1 &= m01 (elements 0-3) ; words 2,3 &= m23 (elements 4-7)
__device__ __forceinline__ void pack8m(const float* v, unsigned m01, unsigned m23,
                                       bf16x8* hi, bf16x8* lo) {
    U4F H, L;
    unsigned* ph = (unsigned*)&H.u;
    unsigned* pl = (unsigned*)&L.u;
    #pragma unroll
    for (int p = 0; p < 4; ++p) {
        float x = v[2*p], y = v[2*p+1];
        unsigned h = pk_bf16(x, y);
        float rx = x - __uint_as_float(h << 16);
        float ry = y - __uint_as_float(h & 0xffff0000u);
        pl[p] = pk_bf16(rx, ry);
        ph[p] = h;
    }
    H.u.x &= m01; H.u.y &= m01; H.u.z &= m23; H.u.w &= m23;
    L.u.x &= m01; L.u.y &= m01; L.u.z &= m23; L.u.w &= m23;
    *hi = H.v; *lo = L.v;
}

// X-plane address (shorts): slot n (0..31), k-octet g (0..3), h (0=hi,1=lo)
__device__ __forceinline__ int xaddr(int n, int g, int h) {
    return n * 64 + ((h ^ (n & 1)) << 5) + ((g ^ ((n >> 1) & 3)) << 3);
}

struct Acc { floatx4 t[2][2]; };

__device__ __forceinline__ void acc_zero(Acc& a) {
    #pragma unroll
    for (int mi = 0; mi < 2; ++mi)
        #pragma unroll
        for (int ni = 0; ni < 2; ++ni)
            a.t[mi][ni] = (floatx4){0.f, 0.f, 0.f, 0.f};
}

__device__ __forceinline__ floatx4 mfma16(bf16x8 a, bf16x8 b, floatx4 c) {
    return __builtin_amdgcn_mfma_f32_16x16x32_bf16(a, b, c, 0, 0, 0);
}

__device__ __forceinline__ void mm12(bf16x8 ah0, bf16x8 ah1, bf16x8 al0, bf16x8 al1,
                                     bf16x8 bh0, bf16x8 bh1, bf16x8 bl0, bf16x8 bl1,
                                     Acc& acc) {
    acc.t[0][0] = mfma16(ah0, bh0, acc.t[0][0]);
    acc.t[0][1] = mfma16(ah0, bh1, acc.t[0][1]);
    acc.t[1][0] = mfma16(ah1, bh0, acc.t[1][0]);
    acc.t[1][1] = mfma16(ah1, bh1, acc.t[1][1]);
    acc.t[0][0] = mfma16(ah0, bl0, acc.t[0][0]);
    acc.t[0][1] = mfma16(ah0, bl1, acc.t[0][1]);
    acc.t[1][0] = mfma16(ah1, bl0, acc.t[1][0]);
    acc.t[1][1] = mfma16(ah1, bl1, acc.t[1][1]);
    acc.t[0][0] = mfma16(al0, bh0, acc.t[0][0]);
    acc.t[0][1] = mfma16(al0, bh1, acc.t[0][1]);
    acc.t[1][0] = mfma16(al1, bh0, acc.t[1][0]);
    acc.t[1][1] = mfma16(al1, bh1, acc.t[1][1]);
}

// B-frags from X plane (4x ds_read_b128)
__device__ __forceinline__ void readB(const unsigned short* X, int n16, int q,
                                      bf16x8* bh0, bf16x8* bh1, bf16x8* bl0, bf16x8* bl1) {
    *bh0 = *(const bf16x8*)(X + xaddr(n16,      q, 0));
    *bl0 = *(const bf16x8*)(X + xaddr(n16,      q, 1));
    *bh1 = *(const bf16x8*)(X + xaddr(16 + n16, q, 0));
    *bl1 = *(const bf16x8*)(X + xaddr(16 + n16, q, 1));
}

// D (C-layout) -> X plane B-conv (8x ds_write_b64)
__device__ __forceinline__ void writeX(unsigned short* X, const Acc& acc,
                                       int n16, int q) {
    const int sub = (q & 1) * 4;
    #pragma unroll
    for (int mi = 0; mi < 2; ++mi) {
        const int g = 2 * mi + (q >> 1);
        #pragma unroll
        for (int ni = 0; ni < 2; ++ni) {
            floatx4 a = acc.t[mi][ni];
            const int n = ni * 16 + n16;
            unsigned h0 = pk_bf16(a[0], a[1]);
            unsigned h1 = pk_bf16(a[2], a[3]);
            float r0 = a[0] - __uint_as_float(h0 << 16);
            float r1 = a[1] - __uint_as_float(h0 & 0xffff0000u);
            float r2 = a[2] - __uint_as_float(h1 << 16);
            float r3 = a[3] - __uint_as_float(h1 & 0xffff0000u);
            unsigned l0 = pk_bf16(r0, r1);
            unsigned l1 = pk_bf16(r2, r3);
            uint2 uh; uh.x = h0; uh.y = h1;
            uint2 ul; ul.x = l0; ul.y = l1;
            *(uint2*)(X + xaddr(n, g, 0) + sub) = uh;
            *(uint2*)(X + xaddr(n, g, 1) + sub) = ul;
        }
    }
}

// D (C-layout) -> A-conv (plain m*32+n, hi | lo+1024) into a plane region
__device__ __forceinline__ void writeAconv(unsigned short* P, const Acc& acc,
                                           int n16, int q) {
    unsigned short* Sh = P;
    unsigned short* Sl = P + 1024;
    #pragma unroll
    for (int mi = 0; mi < 2; ++mi)
        #pragma unroll
        for (int ni = 0; ni < 2; ++ni) {
            floatx4 a = acc.t[mi][ni];
            #pragma unroll
            for (int r = 0; r < 4; ++r) {
                int m = mi * 16 + q * 4 + r;
                int n = ni * 16 + n16;
                int off = m * 32 + n;
                unsigned short hh = f2bf(a[r]);
                Sh[off] = hh;
                Sl[off] = f2bf(a[r] - bf2f(hh));
            }
        }
}

__device__ __forceinline__ void readAconv(const unsigned short* P, int n16, int q,
                                          bf16x8* ah0, bf16x8* ah1,
                                          bf16x8* al0, bf16x8* al1) {
    const unsigned short* Sh = P;
    const unsigned short* Sl = P + 1024;
    const int o0 = n16 * 32 + 8 * q;
    const int o1 = (16 + n16) * 32 + 8 * q;
    *ah0 = *(const bf16x8*)(Sh + o0);
    *ah1 = *(const bf16x8*)(Sh + o1);
    *al0 = *(const bf16x8*)(Sl + o0);
    *al1 = *(const bf16x8*)(Sl + o1);
}

// contiguous A-gather: lane(n16,q) reads M[n16][8q..8q+7] and
// M[16+n16][8q..8q+7] as 4x float4 (q==3 second-half clamped, masked later)
#define GATHER(PA, PB, IDXV) do {                                   \
    const float* bp_ = table + (size_t)(IDXV) * MD2;                \
    *(float4*)((PA)    ) = *(const float4*)(bp_ + offRA0);          \
    *(float4*)((PA) + 4) = *(const float4*)(bp_ + offRA4);          \
    *(float4*)((PB)    ) = *(const float4*)(bp_ + offRB0);          \
    *(float4*)((PB) + 4) = *(const float4*)(bp_ + offRB4);          \
} while (0)

// one chain step: pack A = M_i from (PA,PB), refill that buffer for the
// step after next, fence, read B = G from LDS, 12 MFMA, write G back.
#define CHAINSTEP(J, PA, PB) do {                                   \
    bf16x8 ah0_, ah1_, al0_, al1_;                                  \
    pack8m(PA, ~0u,  mA23, &ah0_, &al0_);                           \
    pack8m(PB, mB01, mB23, &ah1_, &al1_);                           \
    if ((J) >= 2) GATHER(PA, PB, sidx[(J) - 2]);                    \
    LDS_FENCE();                                                    \
    bf16x8 bh0_, bh1_, bl0_, bl1_;                                  \
    readB(Xw, n16, q, &bh0_, &bh1_, &bl0_, &bl1_);                  \
    Acc acc_; acc_zero(acc_);                                       \
    mm12(ah0_, ah1_, al0_, al1_, bh0_, bh1_, bl0_, bl1_, acc_);     \
    if ((J) > 0 || (w & 1) != 0)                                    \
        writeX(Xw, acc_, n16, q);                                   \
    else                                                            \
        writeAconv(Xw, acc_, n16, q);   /* waves 0,2: P_w in A-conv */ \
} while (0)

__global__ __launch_bounds__(256, 4)
void cmow_mfma_kernel(const int* __restrict__ sent,
                      const float* __restrict__ table,
                      float* __restrict__ out)
{
    // 4 planes of 2048 shorts (one per wave) = 16 KB
    __shared__ __align__(16) unsigned short smem[WPB * 2048];

    const int tid  = threadIdx.x;
    const int lane = tid & 63;
    const int w    = tid >> 6;
    const int b    = blockIdx.x;

    unsigned short* Xw = smem + w * 2048;

    // ---- wave-uniform indices -> SGPRs (4x int4 load + readfirstlane)
    const int* sp = sent + b * SEQL + w * CHUNK;
    int sidx[CHUNK];
    {
        const int4* sp4 = (const int4*)sp;
        #pragma unroll
        for (int g = 0; g < CHUNK / 4; ++g) {
            int4 v = sp4[g];
            sidx[4 * g + 0] = __builtin_amdgcn_readfirstlane(v.x);
            sidx[4 * g + 1] = __builtin_amdgcn_readfirstlane(v.y);
            sidx[4 * g + 2] = __builtin_amdgcn_readfirstlane(v.z);
            sidx[4 * g + 3] = __builtin_amdgcn_readfirstlane(v.w);
        }
    }

    const int n16 = lane & 15;
    const int q   = lane >> 4;

    // ---- loop-invariant offsets and padding masks.
    // A-gather (contiguous rows): pa[j] = M[n16][8q+j]; pb[j] = M[16+n16][8q+j]
    //   invalid: k=8q+j>=28 (q==3, j>=4, clamped addr) ; row 16+n16>=28 (n16>=12)
    const int rowB   = (n16 < 12) ? (16 + n16) : 0;
    const int offRA0 = n16 * MD + 8 * q;
    const int offRA4 = n16 * MD + ((q == 3) ? 8 * q : 8 * q + 4);
    const int offRB0 = rowB * MD + 8 * q;
    const int offRB4 = rowB * MD + ((q == 3) ? 8 * q : 8 * q + 4);
    const unsigned mA23 = (q == 3) ? 0u : ~0u;
    const unsigned mB01 = (n16 < 12) ? ~0u : 0u;
    const unsigned mB23 = (n16 < 12 && q != 3) ? ~0u : 0u;

    // init strided gather offsets (B-frags of M_last, once per chunk):
    // pvA[j] = M[8q+j][n16] ; pvB[j] = M[8q+j][16+n16]
    const int colB  = (n16 < 12) ? (16 + n16) : 0;
    const int offS0 = (8 * q) * MD + n16;
    const int offS4 = ((q == 3) ? 0 : (8 * q + 4) * MD) + n16;
    const int offT0 = (8 * q) * MD + colB;
    const int offT4 = ((q == 3) ? 0 : (8 * q + 4) * MD) + colB;

    // ---- prefetch: contiguous A for steps j=14 (buf0) and j=13 (buf1)
    float pa0[8], pb0[8], pa1[8], pb1[8];
    GATHER(pa0, pb0, sidx[14]);

    // strided B-init: G = M_{15}
    float pvA[8], pvB[8];
    {
        const float* bp = table + (size_t)sidx[15] * MD2;
        #pragma unroll
        for (int j = 0; j < 4; ++j) {
            pvA[j]     = bp[offS0 + j * MD];
            pvB[j]     = bp[offT0 + j * MD];
            pvA[4 + j] = bp[offS4 + j * MD];
            pvB[4 + j] = bp[offT4 + j * MD];
        }
    }

    GATHER(pa1, pb1, sidx[13]);

    // ---- step j=14: G = M_14 @ M_15, fully from global (no LDS, no fence)
    {
        bf16x8 ah0, ah1, al0, al1;
        pack8m(pa0, ~0u,  mA23, &ah0, &al0);
        pack8m(pb0, mB01, mB23, &ah1, &al1);

        GATHER(pa0, pb0, sidx[12]);   // refill buf0 for step j=12

        bf16x8 bh0, bh1, bl0, bl1;
        pack8m(pvA, ~0u,  mA23, &bh0, &bl0);  // k>=28 zeroed
        pack8m(pvB, mB01, mB23, &bh1, &bl1);  // n>=28 (and k>=28) zeroed

        Acc acc; acc_zero(acc);
        mm12(ah0, ah1, al0, al1, bh0, bh1, bl0, bl1, acc);
        writeX(Xw, acc, n16, q);
    }

    // ---- steps j=13..0: G = M_j @ G (wave-private plane).
    CHAINSTEP(13, pa1, pb1);
    CHAINSTEP(12, pa0, pb0);
    CHAINSTEP(11, pa1, pb1);
    CHAINSTEP(10, pa0, pb0);
    CHAINSTEP( 9, pa1, pb1);
    CHAINSTEP( 8, pa0, pb0);
    CHAINSTEP( 7, pa1, pb1);
    CHAINSTEP( 6, pa0, pb0);
    CHAINSTEP( 5, pa1, pb1);
    CHAINSTEP( 4, pa0, pb0);
    CHAINSTEP( 3, pa1, pb1);
    CHAINSTEP( 2, pa0, pb0);
    CHAINSTEP( 1, pa1, pb1);
    CHAINSTEP( 0, pa0, pb0);

    // ---- phase 2: left-associative tree. P_w = chunk product (in order).
    // final = P0 @ P1 @ P2 @ P3. Waves 0,2 hold P in A-conv; 1,3 in B-conv.
    __syncthreads();

    if (w < 2) {
        // Y_w = P_{2w} @ P_{2w+1}
        bf16x8 ah0, ah1, al0, al1, bh0, bh1, bl0, bl1;
        readAconv(smem + (2 * w) * 2048, n16, q, &ah0, &ah1, &al0, &al1);
        readB(smem + (2 * w + 1) * 2048, n16, q, &bh0, &bh1, &bl0, &bl1);
        Acc acc; acc_zero(acc);
        mm12(ah0, ah1, al0, al1, bh0, bh1, bl0, bl1, acc);
        if (w == 0) writeAconv(smem, acc, n16, q);             // Y0 -> plane0 (A-conv)
        else        writeX(smem + 2 * 2048, acc, n16, q);      // Y1 -> plane2 (B-conv)
    }
    __syncthreads();

    if (w == 0) {
        // final F = Y0 @ Y1 (C-layout: m = mi*16+q*4+r, n = ni*16+n16)
        bf16x8 ah0, ah1, al0, al1, bh0, bh1, bl0, bl1;
        readAconv(smem, n16, q, &ah0, &ah1, &al0, &al1);
        readB(smem + 2 * 2048, n16, q, &bh0, &bh1, &bl0, &bl1);
        Acc acc; acc_zero(acc);
        mm12(ah0, ah1, al0, al1, bh0, bh1, bl0, bl1, acc);

        float* op = out + (size_t)b * MD2;
        #pragma unroll
        for (int mi = 0; mi < 2; ++mi)
            #pragma unroll
            for (int ni = 0; ni < 2; ++ni) {
                const int n = ni * 16 + n16;
                if (n < MD) {
                    floatx4 a = acc.t[mi][ni];
                    #pragma unroll
                    for (int r = 0; r < 4; ++r) {
                        const int m = mi * 16 + q * 4 + r;
                        if (m < MD) op[m * MD + n] = a[r];
                    }
                }
            }
    }
}

extern "C" void kernel_launch(void* const* d_in, const int* in_sizes, int n_in,
                              void* d_out, int out_size, void* d_ws, size_t ws_size,
                              hipStream_t stream) {
    const int*   sent  = (const int*)d_in[0];
    const float* table = (const float*)d_in[1];
    float*       outp  = (float*)d_out;

    const int batch = in_sizes[0] / SEQL;   // 1024
    cmow_mfma_kernel<<<dim3(batch), dim3(WPB * 64), 0, stream>>>(sent, table, outp);
}